// Round 1
// 214.458 us; speedup vs baseline: 1.0262x; 1.0262x over previous
//
#include <hip/hip_runtime.h>
#include <hip/hip_bf16.h>
#include <math.h>

#define N_ATOM   100000
#define N_QUERY  20000
#define KNN      32

typedef __attribute__((ext_vector_type(8))) short  short8;
typedef __attribute__((ext_vector_type(4))) float  floatx4;
typedef __attribute__((ext_vector_type(2))) float  fx2;

static __device__ __forceinline__ unsigned short f2bf_bits(float f) {
  union { __hip_bfloat16 h; unsigned short u; } cv;
  cv.h = __float2bfloat16(f);
  return cv.u;
}
static __device__ __forceinline__ float bflo(unsigned int u) { return __uint_as_float(u << 16); }
static __device__ __forceinline__ float bfhi(unsigned int u) { return __uint_as_float(u & 0xffff0000u); }

// ---------------- pack ALL weights into MFMA B-fragment order (bf16), one launch ----------------
// dst[((ktile*NT + ntile)*64 + lane)*8 + j] = W^T[ktile*32 + (lane>>4)*8 + j][ntile*16 + (lane&15)]
// NOTE: A-frag and B-frag lane mappings are identical for 16x16x32, so this layout also serves
// as the A-operand when we swap operand roles (W as A => D comes out channel-major per lane).
__global__ void pack_all_kernel(const float* __restrict__ Wq, const float* __restrict__ Wk,
                                const float* __restrict__ Wv, const float* __restrict__ W1,
                                const float* __restrict__ W2,
                                unsigned short* __restrict__ WKVp, unsigned short* __restrict__ WQp,
                                unsigned short* __restrict__ W1p,  unsigned short* __restrict__ W2p) {
  int tid = blockIdx.x * blockDim.x + threadIdx.x;
  if (tid >= 98304) return;
  const float *Wa, *Wb; int nsplit, Kd, Nd; unsigned short* dst; float scale = 1.0f;
  int t = tid;
  if (t < 32768)      { Wa = Wk; Wb = Wv; nsplit = 128; Kd = 128; Nd = 256; dst = WKVp; }
  else if (t < 49152) { t -= 32768; Wa = Wq; Wb = Wq; nsplit = 128; Kd = 128; Nd = 128; dst = WQp; scale = 0.25f; }
  else if (t < 81920) { t -= 49152; Wa = W1; Wb = W1; nsplit = 128; Kd = 256; Nd = 128; dst = W1p; }
  else                { t -= 81920; Wa = W2; Wb = W2; nsplit = 128; Kd = 128; Nd = 128; dst = W2p; }
  int j    = t & 7;
  int lane = (t >> 3) & 63;
  int t2   = t >> 9;
  int NT   = Nd >> 4;
  int ntile = t2 % NT;
  int ktile = t2 / NT;
  int k = ktile * 32 + (lane >> 4) * 8 + j;
  int n = ntile * 16 + (lane & 15);
  float v = (n < nsplit) ? Wa[(size_t)n * Kd + k] : Wb[(size_t)(n - nsplit) * Kd + k];
  dst[t] = f2bf_bits(v * scale);
}

// ---------------- merged KV+Q projection GEMM, SWAPPED operand roles ----------------
// D = mfma(W_frag, x_frag): lane (quad,col0) holds channels n = nt*16 + quad*4 + (0..3)
// for data row col0. KV epilogue: pack 4 consecutive channels into one fp8 dword ->
// 16 ds_write_b32 (stride-160 LDS rows, 4-way conflict) instead of 64 ds_write_b8 (16-way).
__global__ __launch_bounds__(256) void gemm_kvq(
    const float* __restrict__ h_atom, const float* __restrict__ h_query,
    const unsigned short* __restrict__ WKVp, const unsigned short* __restrict__ WQp,
    unsigned char* __restrict__ Kp8, unsigned char* __restrict__ Vp8,
    unsigned short* __restrict__ Qb) {
  constexpr int KB = (N_ATOM + 63) / 64;
  constexpr int LSTR = 160;                  // LDS row stride (bytes): 16B-aligned, 4-way write / 2-way read
  __shared__ char lds[2 * 64 * LSTR];        // K rows at 0, V rows at 64*LSTR
  const int l    = threadIdx.x & 63;
  const int w    = threadIdx.x >> 6;
  const int quad = l >> 4;
  const int col0 = l & 15;

  if ((int)blockIdx.x < KB) {
    const int row0 = blockIdx.x * 64 + w * 16;
    int arow = row0 + col0;
    if (arow >= N_ATOM) arow = N_ATOM - 1;

    // prefetch the whole A-row slice for this lane: 4 k-iters x 2 float4
    const float* aptr = h_atom + (size_t)arow * 128 + quad * 8;
    floatx4 a[8];
#pragma unroll
    for (int k0 = 0; k0 < 4; k0++) {
      a[2 * k0]     = *(const floatx4*)(aptr + k0 * 32);
      a[2 * k0 + 1] = *(const floatx4*)(aptr + k0 * 32 + 4);
    }
    short8 af[4];
#pragma unroll
    for (int k0 = 0; k0 < 4; k0++) {
      af[k0][0] = (short)f2bf_bits(a[2*k0][0]); af[k0][1] = (short)f2bf_bits(a[2*k0][1]);
      af[k0][2] = (short)f2bf_bits(a[2*k0][2]); af[k0][3] = (short)f2bf_bits(a[2*k0][3]);
      af[k0][4] = (short)f2bf_bits(a[2*k0+1][0]); af[k0][5] = (short)f2bf_bits(a[2*k0+1][1]);
      af[k0][6] = (short)f2bf_bits(a[2*k0+1][2]); af[k0][7] = (short)f2bf_bits(a[2*k0+1][3]);
    }

    floatx4 acc[16];
#pragma unroll
    for (int i = 0; i < 16; i++) acc[i] = (floatx4){0.f, 0.f, 0.f, 0.f};
#pragma unroll
    for (int k0 = 0; k0 < 4; k0++) {
      const unsigned short* bbase = WKVp + (size_t)k0 * 16 * 512 + l * 8;
#pragma unroll
      for (int nt = 0; nt < 16; nt++) {
        short8 bf = *(const short8*)(bbase + nt * 512);
        acc[nt] = __builtin_amdgcn_mfma_f32_16x16x32_bf16(bf, af[k0], acc[nt], 0, 0, 0);  // SWAPPED
      }
    }
    // lane holds channels nt*16+quad*4+(0..3) of local row (w*16+col0): pack 4 fp8 -> 1 dword
    {
      const int rl = w * 16 + col0;
#pragma unroll
      for (int nt = 0; nt < 16; nt++) {
        int pk = __builtin_amdgcn_cvt_pk_fp8_f32(acc[nt][0], acc[nt][1], 0, false);
        pk     = __builtin_amdgcn_cvt_pk_fp8_f32(acc[nt][2], acc[nt][3], pk, true);
        const int c = nt * 16 + quad * 4;
        if (c < 128) *(int*)&lds[rl * LSTR + c] = pk;                    // K half
        else         *(int*)&lds[64 * LSTR + rl * LSTR + (c - 128)] = pk; // V half
      }
    }
    __syncthreads();
    const int row0g = blockIdx.x * 64;
#pragma unroll
    for (int it = 0; it < 2; it++) {
      int linear = threadIdx.x * 16 + it * 4096;
      int row = linear >> 7, col = linear & 127;
      if (row0g + row < N_ATOM)
        *(float4*)(Kp8 + (size_t)(row0g + row) * 128 + col) = *(const float4*)&lds[row * LSTR + col];
    }
#pragma unroll
    for (int it = 0; it < 2; it++) {
      int linear = threadIdx.x * 16 + it * 4096;
      int row = linear >> 7, col = linear & 127;
      if (row0g + row < N_ATOM)
        *(float4*)(Vp8 + (size_t)(row0g + row) * 128 + col) = *(const float4*)&lds[64 * LSTR + row * LSTR + col];
    }
  } else {
    const int row0 = ((int)blockIdx.x - KB) * 64 + w * 16;
    int arow = row0 + col0;
    if (arow >= N_QUERY) arow = N_QUERY - 1;
    floatx4 acc[8];
#pragma unroll
    for (int i = 0; i < 8; i++) acc[i] = (floatx4){0.f, 0.f, 0.f, 0.f};
    const float* aptr = h_query + (size_t)arow * 128 + quad * 8;
#pragma unroll
    for (int k0 = 0; k0 < 128; k0 += 32) {
      floatx4 a0 = *(const floatx4*)(aptr + k0);
      floatx4 a1 = *(const floatx4*)(aptr + k0 + 4);
      short8 af;
      af[0] = (short)f2bf_bits(a0[0]); af[1] = (short)f2bf_bits(a0[1]);
      af[2] = (short)f2bf_bits(a0[2]); af[3] = (short)f2bf_bits(a0[3]);
      af[4] = (short)f2bf_bits(a1[0]); af[5] = (short)f2bf_bits(a1[1]);
      af[6] = (short)f2bf_bits(a1[2]); af[7] = (short)f2bf_bits(a1[3]);
      const unsigned short* bbase = WQp + (size_t)(k0 >> 5) * 8 * 512 + l * 8;
#pragma unroll
      for (int nt = 0; nt < 8; nt++) {
        short8 bf = *(const short8*)(bbase + nt * 512);
        acc[nt] = __builtin_amdgcn_mfma_f32_16x16x32_bf16(bf, af, acc[nt], 0, 0, 0);  // SWAPPED
      }
    }
    // lane holds channels nt*16+quad*4+(0..3) bf16 of row (row0+col0): 8-byte stores
    const int row = row0 + col0;
    if (row < N_QUERY) {
#pragma unroll
      for (int nt = 0; nt < 8; nt++) {
        unsigned u0 = (unsigned)f2bf_bits(acc[nt][0]) | ((unsigned)f2bf_bits(acc[nt][1]) << 16);
        unsigned u1 = (unsigned)f2bf_bits(acc[nt][2]) | ((unsigned)f2bf_bits(acc[nt][3]) << 16);
        uint2 uu; uu.x = u0; uu.y = u1;
        *(uint2*)(Qb + (size_t)row * 128 + nt * 16 + quad * 4) = uu;
      }
    }
  }
}

// ---------------- attention: all gathers hoisted; reduce-scatter epilogue ----------------
// Wave per query. Lane l: j = l>>3 (edge slot), h = l&7 (head).
// Issue order: src row -> ea(pass0,1) -> Q -> Wrbf -> 4 shfls -> ALL 8 K/V gathers ->
// ea(pass2,3) staged around ed computation. ONE latency window instead of four.
// Epilogue: 3-step reduce-scatter (14 shfl) leaves 2 dims/lane -> one float2 store/lane.
__global__ __launch_bounds__(256, 4) void attn_kernel(
    const unsigned short* __restrict__ Qb,    // [N_QUERY][128] bf16 (pre-scaled 1/sqrt(16))
    const unsigned char* __restrict__ Kp8,    // [N_ATOM][128] fp8 e4m3
    const unsigned char* __restrict__ Vp8,    // [N_ATOM][128] fp8 e4m3
    const float* __restrict__ edge_attr,      // [E][16]
    const float* __restrict__ Wrbf,           // [8][16]
    const int* __restrict__ src,              // [E]
    float* __restrict__ Agg) {                // [N_QUERY][128]
  const int l = threadIdx.x & 63;
  const int w = threadIdx.x >> 6;
  const int q = blockIdx.x * 4 + w;
  const int j = l >> 3;
  const int h = l & 7;
  const int e0 = q * KNN;

  // ---- issue phase ----
  int srcj = (l < KNN) ? src[e0 + l] : 0;

  const float4* ep0 = (const float4*)(edge_attr + (size_t)(e0 +  0 + j) * 16);
  const float4* ep1 = (const float4*)(edge_attr + (size_t)(e0 +  8 + j) * 16);
  const float4* ep2 = (const float4*)(edge_attr + (size_t)(e0 + 16 + j) * 16);
  const float4* ep3 = (const float4*)(edge_attr + (size_t)(e0 + 24 + j) * 16);
  float4 a0 = ep0[0], a1 = ep0[1], a2 = ep0[2], a3 = ep0[3];
  float4 b0 = ep1[0], b1 = ep1[1], b2 = ep1[2], b3 = ep1[3];

  const uint4* qp = (const uint4*)(Qb + (size_t)q * 128 + h * 16);
  uint4 qA = qp[0], qB = qp[1];
  const float4* wp = (const float4*)(Wrbf + h * 16);
  float4 w0 = wp[0], w1 = wp[1], w2 = wp[2], w3 = wp[3];

  int s0 = __shfl(srcj,      j, 64);
  int s1 = __shfl(srcj,  8 + j, 64);
  int s2 = __shfl(srcj, 16 + j, 64);
  int s3 = __shfl(srcj, 24 + j, 64);

  uint4 kq0 = *(const uint4*)(Kp8 + (size_t)s0 * 128 + h * 16);
  uint4 kq1 = *(const uint4*)(Kp8 + (size_t)s1 * 128 + h * 16);
  uint4 kq2 = *(const uint4*)(Kp8 + (size_t)s2 * 128 + h * 16);
  uint4 kq3 = *(const uint4*)(Kp8 + (size_t)s3 * 128 + h * 16);
  uint4 vq0 = *(const uint4*)(Vp8 + (size_t)s0 * 128 + h * 16);
  uint4 vq1 = *(const uint4*)(Vp8 + (size_t)s1 * 128 + h * 16);
  uint4 vq2 = *(const uint4*)(Vp8 + (size_t)s2 * 128 + h * 16);
  uint4 vq3 = *(const uint4*)(Vp8 + (size_t)s3 * 128 + h * 16);

  float4 c0 = ep2[0], c1 = ep2[1], c2 = ep2[2], c3 = ep2[3];

  float ed0 = w0.x*a0.x + w0.y*a0.y + w0.z*a0.z + w0.w*a0.w
            + w1.x*a1.x + w1.y*a1.y + w1.z*a1.z + w1.w*a1.w
            + w2.x*a2.x + w2.y*a2.y + w2.z*a2.z + w2.w*a2.w
            + w3.x*a3.x + w3.y*a3.y + w3.z*a3.z + w3.w*a3.w;

  float4 d0 = ep3[0], d1 = ep3[1], d2 = ep3[2], d3 = ep3[3];

  float ed1 = w0.x*b0.x + w0.y*b0.y + w0.z*b0.z + w0.w*b0.w
            + w1.x*b1.x + w1.y*b1.y + w1.z*b1.z + w1.w*b1.w
            + w2.x*b2.x + w2.y*b2.y + w2.z*b2.z + w2.w*b2.w
            + w3.x*b3.x + w3.y*b3.y + w3.z*b3.z + w3.w*b3.w;
  float ed2 = w0.x*c0.x + w0.y*c0.y + w0.z*c0.z + w0.w*c0.w
            + w1.x*c1.x + w1.y*c1.y + w1.z*c1.z + w1.w*c1.w
            + w2.x*c2.x + w2.y*c2.y + w2.z*c2.z + w2.w*c2.w
            + w3.x*c3.x + w3.y*c3.y + w3.z*c3.z + w3.w*c3.w;
  float ed3 = w0.x*d0.x + w0.y*d0.y + w0.z*d0.z + w0.w*d0.w
            + w1.x*d1.x + w1.y*d1.y + w1.z*d1.z + w1.w*d1.w
            + w2.x*d2.x + w2.y*d2.y + w2.z*d2.z + w2.w*d2.w
            + w3.x*d3.x + w3.y*d3.y + w3.z*d3.z + w3.w*d3.w;

  // unpack Q after loads are in flight
  float qd[16];
  qd[0]  = bflo(qA.x); qd[1]  = bfhi(qA.x); qd[2]  = bflo(qA.y); qd[3]  = bfhi(qA.y);
  qd[4]  = bflo(qA.z); qd[5]  = bfhi(qA.z); qd[6]  = bflo(qA.w); qd[7]  = bfhi(qA.w);
  qd[8]  = bflo(qB.x); qd[9]  = bfhi(qB.x); qd[10] = bflo(qB.y); qd[11] = bfhi(qB.y);
  qd[12] = bflo(qB.z); qd[13] = bfhi(qB.z); qd[14] = bflo(qB.w); qd[15] = bfhi(qB.w);

  float acc[16];
#pragma unroll
  for (int i = 0; i < 16; i++) acc[i] = 0.f;
  float lsum = 0.f;

  auto dopass = [&](const uint4& kq, const uint4& vq, float ed) {
    float kd = 0.f;
    {
      fx2 f0, f1;
      f0 = __builtin_amdgcn_cvt_pk_f32_fp8((int)kq.x, false);
      f1 = __builtin_amdgcn_cvt_pk_f32_fp8((int)kq.x, true);
      kd += qd[0] * f0[0] + qd[1] * f0[1] + qd[2] * f1[0] + qd[3] * f1[1];
      f0 = __builtin_amdgcn_cvt_pk_f32_fp8((int)kq.y, false);
      f1 = __builtin_amdgcn_cvt_pk_f32_fp8((int)kq.y, true);
      kd += qd[4] * f0[0] + qd[5] * f0[1] + qd[6] * f1[0] + qd[7] * f1[1];
      f0 = __builtin_amdgcn_cvt_pk_f32_fp8((int)kq.z, false);
      f1 = __builtin_amdgcn_cvt_pk_f32_fp8((int)kq.z, true);
      kd += qd[8] * f0[0] + qd[9] * f0[1] + qd[10] * f1[0] + qd[11] * f1[1];
      f0 = __builtin_amdgcn_cvt_pk_f32_fp8((int)kq.w, false);
      f1 = __builtin_amdgcn_cvt_pk_f32_fp8((int)kq.w, true);
      kd += qd[12] * f0[0] + qd[13] * f0[1] + qd[14] * f1[0] + qd[15] * f1[1];
    }
    float pe = __expf(kd + ed);
    lsum += pe;
    {
      fx2 g0, g1;
      g0 = __builtin_amdgcn_cvt_pk_f32_fp8((int)vq.x, false);
      g1 = __builtin_amdgcn_cvt_pk_f32_fp8((int)vq.x, true);
      acc[0] += pe * g0[0]; acc[1] += pe * g0[1]; acc[2] += pe * g1[0]; acc[3] += pe * g1[1];
      g0 = __builtin_amdgcn_cvt_pk_f32_fp8((int)vq.y, false);
      g1 = __builtin_amdgcn_cvt_pk_f32_fp8((int)vq.y, true);
      acc[4] += pe * g0[0]; acc[5] += pe * g0[1]; acc[6] += pe * g1[0]; acc[7] += pe * g1[1];
      g0 = __builtin_amdgcn_cvt_pk_f32_fp8((int)vq.z, false);
      g1 = __builtin_amdgcn_cvt_pk_f32_fp8((int)vq.z, true);
      acc[8] += pe * g0[0]; acc[9] += pe * g0[1]; acc[10] += pe * g1[0]; acc[11] += pe * g1[1];
      g0 = __builtin_amdgcn_cvt_pk_f32_fp8((int)vq.w, false);
      g1 = __builtin_amdgcn_cvt_pk_f32_fp8((int)vq.w, true);
      acc[12] += pe * g0[0]; acc[13] += pe * g0[1]; acc[14] += pe * g1[0]; acc[15] += pe * g1[1];
    }
  };
  dopass(kq0, vq0, ed0);
  dopass(kq1, vq1, ed1);
  dopass(kq2, vq2, ed2);
  dopass(kq3, vq3, ed3);

  // lsum: full butterfly over j
  lsum += __shfl_xor(lsum, 8, 64);
  lsum += __shfl_xor(lsum, 16, 64);
  lsum += __shfl_xor(lsum, 32, 64);

  // acc: reduce-scatter over j -> each lane ends with dims {h*16 + 2j, +1}
  float r8[8];
  const bool hiA = (l & 32) != 0;
#pragma unroll
  for (int i = 0; i < 8; i++) {
    float keep = hiA ? acc[i + 8] : acc[i];
    float send = hiA ? acc[i]     : acc[i + 8];
    r8[i] = keep + __shfl_xor(send, 32, 64);
  }
  float r4[4];
  const bool hiB = (l & 16) != 0;
#pragma unroll
  for (int i = 0; i < 4; i++) {
    float keep = hiB ? r8[i + 4] : r8[i];
    float send = hiB ? r8[i]     : r8[i + 4];
    r4[i] = keep + __shfl_xor(send, 16, 64);
  }
  float r2[2];
  const bool hiC = (l & 8) != 0;
#pragma unroll
  for (int i = 0; i < 2; i++) {
    float keep = hiC ? r4[i + 1 + 1] : r4[i];
    float send = hiC ? r4[i]         : r4[i + 2];
    r2[i] = keep + __shfl_xor(send, 8, 64);
  }
  float inv = 1.f / (lsum + 1e-16f);
  float2 o; o.x = r2[0] * inv; o.y = r2[1] * inv;
  *(float2*)(Agg + (size_t)q * 128 + h * 16 + 2 * j) = o;
}

// ---------------- fused MLP (swapped MFMA roles): relu(z@W1^T+b1)@W2^T + b2 + resid -> LN ------
__global__ __launch_bounds__(256) void mlp_kernel(
    const float* __restrict__ h_query, const float* __restrict__ Agg,
    const unsigned short* __restrict__ W1p, const unsigned short* __restrict__ W2p,
    const float* __restrict__ b1, const float* __restrict__ b2,
    const float* __restrict__ gamma, const float* __restrict__ beta,
    float* __restrict__ out) {
  constexpr int M = N_QUERY;
  constexpr int STRIDE = 136;               // ushorts per LDS row (272 B)
  __shared__ unsigned short hid[64 * STRIDE];

  const int l    = threadIdx.x & 63;
  const int w    = threadIdx.x >> 6;
  const int quad = l >> 4;
  const int col0 = l & 15;
  const int row0 = blockIdx.x * 64 + w * 16;
  int arow = row0 + col0;
  if (arow >= M) arow = M - 1;

  floatx4 acc[8];
#pragma unroll
  for (int i = 0; i < 8; i++) acc[i] = (floatx4){0.f, 0.f, 0.f, 0.f};
#pragma unroll
  for (int k0 = 0; k0 < 256; k0 += 32) {
    const float* sp = (k0 < 128) ? (h_query + (size_t)arow * 128 + k0)
                                 : (Agg + (size_t)arow * 128 + (k0 - 128));
    floatx4 a0 = *(const floatx4*)(sp + quad * 8);
    floatx4 a1 = *(const floatx4*)(sp + quad * 8 + 4);
    short8 af;
    af[0] = (short)f2bf_bits(a0[0]); af[1] = (short)f2bf_bits(a0[1]);
    af[2] = (short)f2bf_bits(a0[2]); af[3] = (short)f2bf_bits(a0[3]);
    af[4] = (short)f2bf_bits(a1[0]); af[5] = (short)f2bf_bits(a1[1]);
    af[6] = (short)f2bf_bits(a1[2]); af[7] = (short)f2bf_bits(a1[3]);
    const unsigned short* bbase = W1p + (size_t)(k0 >> 5) * 8 * 512 + l * 8;
#pragma unroll
    for (int nt = 0; nt < 8; nt++) {
      short8 bf = *(const short8*)(bbase + nt * 512);
      acc[nt] = __builtin_amdgcn_mfma_f32_16x16x32_bf16(bf, af, acc[nt], 0, 0, 0);  // SWAPPED
    }
  }
  // lane holds hidden channels nt*16+quad*4+(0..3) of local row (w*16+col0): 8-B LDS stores
  {
    const int rl = w * 16 + col0;
#pragma unroll
    for (int nt = 0; nt < 8; nt++) {
      const int c = nt * 16 + quad * 4;
      float4 bb = *(const float4*)(b1 + c);
      unsigned u0 = (unsigned)f2bf_bits(fmaxf(acc[nt][0] + bb.x, 0.f))
                  | ((unsigned)f2bf_bits(fmaxf(acc[nt][1] + bb.y, 0.f)) << 16);
      unsigned u1 = (unsigned)f2bf_bits(fmaxf(acc[nt][2] + bb.z, 0.f))
                  | ((unsigned)f2bf_bits(fmaxf(acc[nt][3] + bb.w, 0.f)) << 16);
      uint2 uu; uu.x = u0; uu.y = u1;
      *(uint2*)(hid + rl * STRIDE + c) = uu;
    }
  }
  __syncthreads();

  floatx4 acc2[8];
#pragma unroll
  for (int i = 0; i < 8; i++) acc2[i] = (floatx4){0.f, 0.f, 0.f, 0.f};
  const int rloc = w * 16 + col0;
#pragma unroll
  for (int k0 = 0; k0 < 128; k0 += 32) {
    short8 af = *(const short8*)(hid + rloc * STRIDE + k0 + quad * 8);
    const unsigned short* bbase = W2p + (size_t)(k0 >> 5) * 8 * 512 + l * 8;
#pragma unroll
    for (int nt = 0; nt < 8; nt++) {
      short8 bf = *(const short8*)(bbase + nt * 512);
      acc2[nt] = __builtin_amdgcn_mfma_f32_16x16x32_bf16(bf, af, acc2[nt], 0, 0, 0);  // SWAPPED
    }
  }

  // lane owns 32 channels (nt*16+quad*4+0..3) of ONE row (row0+col0): LN per lane, reduce over quad
  const int rowq = row0 + col0;
  const int rr   = rowq < M ? rowq : M - 1;
  float v[8][4];
  float s1 = 0.f, s2 = 0.f;
#pragma unroll
  for (int nt = 0; nt < 8; nt++) {
    const int c = nt * 16 + quad * 4;
    float4 hq = *(const float4*)(h_query + (size_t)rr * 128 + c);
    float4 bb = *(const float4*)(b2 + c);
    float t0 = acc2[nt][0] + bb.x + hq.x;
    float t1 = acc2[nt][1] + bb.y + hq.y;
    float t2 = acc2[nt][2] + bb.z + hq.z;
    float t3 = acc2[nt][3] + bb.w + hq.w;
    v[nt][0] = t0; v[nt][1] = t1; v[nt][2] = t2; v[nt][3] = t3;
    s1 += t0 + t1 + t2 + t3;
    s2 += t0 * t0 + t1 * t1 + t2 * t2 + t3 * t3;
  }
  s1 += __shfl_xor(s1, 16, 64); s1 += __shfl_xor(s1, 32, 64);
  s2 += __shfl_xor(s2, 16, 64); s2 += __shfl_xor(s2, 32, 64);
  float mean = s1 * (1.0f / 128.0f);
  float var  = s2 * (1.0f / 128.0f) - mean * mean;
  float rstd = rsqrtf(var + 1e-5f);
  if (rowq < M) {
#pragma unroll
    for (int nt = 0; nt < 8; nt++) {
      const int c = nt * 16 + quad * 4;
      float4 gg = *(const float4*)(gamma + c);
      float4 be = *(const float4*)(beta + c);
      float4 o;
      o.x = (v[nt][0] - mean) * rstd * gg.x + be.x;
      o.y = (v[nt][1] - mean) * rstd * gg.y + be.y;
      o.z = (v[nt][2] - mean) * rstd * gg.z + be.z;
      o.w = (v[nt][3] - mean) * rstd * gg.w + be.w;
      *(float4*)(out + (size_t)rowq * 128 + c) = o;
    }
  }
}

extern "C" void kernel_launch(void* const* d_in, const int* in_sizes, int n_in,
                              void* d_out, int out_size, void* d_ws, size_t ws_size,
                              hipStream_t stream) {
  const float* h_atom    = (const float*)d_in[0];
  const float* h_query   = (const float*)d_in[1];
  const float* edge_attr = (const float*)d_in[2];
  const float* W_q  = (const float*)d_in[3];
  const float* W_k  = (const float*)d_in[4];
  const float* W_v  = (const float*)d_in[5];
  const float* Wrbf = (const float*)d_in[6];
  const float* W1   = (const float*)d_in[7];
  const float* b1   = (const float*)d_in[8];
  const float* W2   = (const float*)d_in[9];
  const float* b2   = (const float*)d_in[10];
  const float* ln_g = (const float*)d_in[11];
  const float* ln_b = (const float*)d_in[12];
  const int* edge_index = (const int*)d_in[13];   // [0..E) = src
  float* out = (float*)d_out;

  char* ws = (char*)d_ws;
  unsigned char*  Kp8 = (unsigned char*)(ws);                  // 100000*128 B = 12.8 MB
  unsigned char*  Vp8 = (unsigned char*)(ws + 12800000);       // 100000*128 B = 12.8 MB
  unsigned short* Qb  = (unsigned short*)(ws + 25600000);      // 20000*128 bf16 = 5.12 MB
  float* Agg          = (float*)(ws + 30720000);               // 20000*128 f32  = 10.24 MB
  unsigned short* WKVp = (unsigned short*)(ws + 40960000);     // 128x256
  unsigned short* WQp  = WKVp + 32768;                         // 128x128
  unsigned short* W1p  = WQp  + 16384;                         // 256x128
  unsigned short* W2p  = W1p  + 32768;                         // 128x128

  pack_all_kernel<<<(98304 + 255) / 256, 256, 0, stream>>>(
      W_q, W_k, W_v, W1, W2, WKVp, WQp, W1p, W2p);

  // merged: K(fp8)/V(fp8) = h_atom @ [W_k|W_v]^T  and  Q(bf16) = h_query @ (W_q/4)^T
  constexpr int KB = (N_ATOM + 63) / 64;
  constexpr int QB = (N_QUERY + 63) / 64;
  gemm_kvq<<<KB + QB, 256, 0, stream>>>(h_atom, h_query, WKVp, WQp, Kp8, Vp8, Qb);

  // attention -> Agg
  attn_kernel<<<N_QUERY / 4, 256, 0, stream>>>(Qb, Kp8, Vp8, edge_attr, Wrbf, edge_index, Agg);

  // fused MLP + residual + LayerNorm -> out
  mlp_kernel<<<(N_QUERY + 63) / 64, 256, 0, stream>>>(
      h_query, Agg, W1p, W2p, b1, b2, ln_g, ln_b, out);
}